// Round 5
// baseline (291.673 us; speedup 1.0000x reference)
//
#include <hip/hip_runtime.h>
#include <hip/hip_bf16.h>
#include <stdint.h>
#include <stddef.h>

#define EMBED 1024
#define NHEAD 16
#define HDIM  64
#define BATCH 2
#define SEQ   2048
#define MTOT  (BATCH*SEQ)

typedef __hip_bfloat16 bf16;
typedef __attribute__((ext_vector_type(8))) __bf16 bf16x8;
typedef __attribute__((ext_vector_type(4))) float  f32x4;

// async global->LDS, 16B per lane. LDS dest must be wave-uniform base + lane*16.
#define GLD16(gp, lp) __builtin_amdgcn_global_load_lds( \
    (__attribute__((address_space(1))) void*)(gp),      \
    (__attribute__((address_space(3))) void*)(lp), 16, 0, 0)

__device__ __forceinline__ ushort4 cvt4(const float4 v) {
  union { ushort4 u; bf16 b[4]; } o;
  o.b[0] = __float2bfloat16(v.x);
  o.b[1] = __float2bfloat16(v.y);
  o.b[2] = __float2bfloat16(v.z);
  o.b[3] = __float2bfloat16(v.w);
  return o.u;
}

// Per-block dtype vote (replaces the detect dispatch). Every wave samples the
// same 64 words of the query buffer -> identical ballot -> block-uniform.
// bf16 data: low half-words have sane exponents (~64/64); fp32: ~9/64.
__device__ __forceinline__ bool detect_bf16(const uint32_t* __restrict__ x, int t) {
  uint32_t w = x[(size_t)(t & 63) * 997u];
  int e = (int)((w >> 7) & 0xFF);
  unsigned long long m = __ballot(e >= 100 && e <= 135);
  return __popcll(m) >= 48;
}

// ---------------------------------------------------------------------------
// HOT PATH: NT GEMM, TMxTN tile, BK=64, double-buffered LDS, raw s_barrier +
// fine vmcnt (prefetch stays in flight across the barrier — AITER pattern).
// 2x2 wave grid: wave covers (TM/2)x(TN/2); RI=TM/32, RJ=TN/32 frags.
// ---------------------------------------------------------------------------
template<int TM, int TN>
__device__ __forceinline__ void gemm_nt_dbuf(
    const bf16* __restrict__ X, const bf16* __restrict__ W,
    bf16* sA, bf16* sB, f32x4 (&acc)[TM/32][TN/32],
    int row0, int col0, int t, int wr, int wc, int l16, int quad) {
  constexpr int CA  = TM / 32;        // GLD16 chunks for A per iter
  constexpr int CB  = TN / 32;
  constexpr int RI  = TM / 32;
  constexpr int RJ  = TN / 32;
  constexpr int NIT = EMBED / 64;     // 16
  constexpr int PF  = CA + CB;        // loads in flight per iter

  const bf16* gA[CA]; const bf16* gB[CB];
  int la[CA], lb[CB];
#pragma unroll
  for (int c = 0; c < CA; ++c) {
    int id = c * 256 + t, r = id >> 3, cc = (id & 7) * 8;
    gA[c] = X + (size_t)(row0 + r) * EMBED + cc;  la[c] = id * 8;
  }
#pragma unroll
  for (int c = 0; c < CB; ++c) {
    int id = c * 256 + t, r = id >> 3, cc = (id & 7) * 8;
    gB[c] = W + (size_t)(col0 + r) * EMBED + cc;  lb[c] = id * 8;
  }

  auto issue = [&](int kb, int buf) {
#pragma unroll
    for (int c = 0; c < CA; ++c) GLD16(gA[c] + kb, sA + buf * (TM * 64) + la[c]);
#pragma unroll
    for (int c = 0; c < CB; ++c) GLD16(gB[c] + kb, sB + buf * (TN * 64) + lb[c]);
  };
  auto compute = [&](int buf) {
    const bf16* pA = sA + buf * (TM * 64);
    const bf16* pB = sB + buf * (TN * 64);
#pragma unroll
    for (int kk = 0; kk < 64; kk += 32) {
      bf16x8 a[RI], b[RJ];
#pragma unroll
      for (int i = 0; i < RI; ++i)
        a[i] = *(const bf16x8*)(pA + (wr + 16 * i + l16) * 64 + kk + quad * 8);
#pragma unroll
      for (int j = 0; j < RJ; ++j)
        b[j] = *(const bf16x8*)(pB + (wc + 16 * j + l16) * 64 + kk + quad * 8);
#pragma unroll
      for (int i = 0; i < RI; ++i)
#pragma unroll
        for (int j = 0; j < RJ; ++j)
          acc[i][j] = __builtin_amdgcn_mfma_f32_16x16x32_bf16(a[i], b[j], acc[i][j], 0, 0, 0);
    }
  };

  issue(0, 0);
  int p = 0;
  for (int i = 0; i < NIT - 1; ++i) {
    issue((i + 1) * 64, p ^ 1);
    asm volatile("s_waitcnt vmcnt(%0)\ns_barrier" :: "i"(PF) : "memory");
    compute(p);
    asm volatile("s_barrier" ::: "memory");
    p ^= 1;
  }
  asm volatile("s_waitcnt vmcnt(0)\ns_barrier" ::: "memory");
  compute(p);
}

// ---------------------------------------------------------------------------
// SLOW PATH (fp32 inputs; insurance only). Single buffer, __syncthreads.
// ---------------------------------------------------------------------------
template<int TM, int TN, bool ABF, bool BBF>
__device__ __forceinline__ void gemm_nt_slow(
    const void* __restrict__ X, const void* __restrict__ W,
    bf16* sA, bf16* sB, f32x4 (&acc)[TM/32][TN/32],
    int row0, int col0, int t, int wr, int wc, int l16, int quad) {
  constexpr int RI = TM / 32, RJ = TN / 32;
  for (int kb = 0; kb < EMBED; kb += 64) {
    if constexpr (ABF) {
      const bf16* s = (const bf16*)X;
#pragma unroll
      for (int c = 0; c < TM / 32; ++c) {
        int id = c * 256 + t, r = id >> 3, cc = (id & 7) * 8;
        GLD16(s + (size_t)(row0 + r) * EMBED + kb + cc, sA + id * 8);
      }
    } else {
      const float* s = (const float*)X;
#pragma unroll
      for (int c = 0; c < TM / 16; ++c) {
        int id = c * 256 + t, r = id >> 4, cc = (id & 15) * 4;
        float4 v = *(const float4*)(s + (size_t)(row0 + r) * EMBED + kb + cc);
        *(ushort4*)(sA + r * 64 + cc) = cvt4(v);
      }
    }
    if constexpr (BBF) {
      const bf16* s = (const bf16*)W;
#pragma unroll
      for (int c = 0; c < TN / 32; ++c) {
        int id = c * 256 + t, r = id >> 3, cc = (id & 7) * 8;
        GLD16(s + (size_t)(col0 + r) * EMBED + kb + cc, sB + id * 8);
      }
    } else {
      const float* s = (const float*)W;
#pragma unroll
      for (int c = 0; c < TN / 16; ++c) {
        int id = c * 256 + t, r = id >> 4, cc = (id & 15) * 4;
        float4 v = *(const float4*)(s + (size_t)(col0 + r) * EMBED + kb + cc);
        *(ushort4*)(sB + r * 64 + cc) = cvt4(v);
      }
    }
    __syncthreads();
#pragma unroll
    for (int kk = 0; kk < 64; kk += 32) {
      bf16x8 a[RI], b[RJ];
#pragma unroll
      for (int i = 0; i < RI; ++i)
        a[i] = *(const bf16x8*)(sA + (wr + 16 * i + l16) * 64 + kk + quad * 8);
#pragma unroll
      for (int j = 0; j < RJ; ++j)
        b[j] = *(const bf16x8*)(sB + (wc + 16 * j + l16) * 64 + kk + quad * 8);
#pragma unroll
      for (int i = 0; i < RI; ++i)
#pragma unroll
        for (int j = 0; j < RJ; ++j)
          acc[i][j] = __builtin_amdgcn_mfma_f32_16x16x32_bf16(a[i], b[j], acc[i][j], 0, 0, 0);
    }
    __syncthreads();
  }
}

// Fused QKV projection, 64x128 tiles. Grid (64, 24): blockIdx.y [0..7]=Q,
// [8..15]=K, [16..23]=V. Q,K row-major bf16; V transposed [B][H][D][S].
__global__ __launch_bounds__(256, 3)
void qkv_proj_kernel(const void* Xq, const void* Xk, const void* Xv,
                     const void* Wq, const void* Wk, const void* Wv,
                     bf16* __restrict__ Qo, bf16* __restrict__ Ko,
                     bf16* __restrict__ Vto) {
  __shared__ __align__(16) bf16 sA[2 * 64 * 64];
  __shared__ __align__(16) bf16 sB[2 * 128 * 64];
  const int t    = threadIdx.x;
  const int wave = t >> 6, lane = t & 63;
  const int quad = lane >> 4, l16 = lane & 15;
  const int row0 = blockIdx.x * 64;
  const int sel  = blockIdx.y >> 3;
  const int col0 = (blockIdx.y & 7) * 128;
  const int wr = (wave & 1) * 32;
  const int wc = (wave >> 1) * 64;

  const void* X = (sel == 0) ? Xq : (sel == 1) ? Xk : Xv;
  const void* W = (sel == 0) ? Wq : (sel == 1) ? Wk : Wv;

  f32x4 acc[2][4] = {};
  if (detect_bf16((const uint32_t*)Xq, t))
    gemm_nt_dbuf<64, 128>((const bf16*)X, (const bf16*)W, sA, sB, acc,
                          row0, col0, t, wr, wc, l16, quad);
  else
    gemm_nt_slow<64, 128, false, false>(X, W, sA, sB, acc,
                                        row0, col0, t, wr, wc, l16, quad);

  if (sel < 2) {
    bf16* C = (sel == 0) ? Qo : Ko;
#pragma unroll
    for (int i = 0; i < 2; ++i)
#pragma unroll
      for (int j = 0; j < 4; ++j)
#pragma unroll
        for (int r = 0; r < 4; ++r) {
          int m = row0 + wr + 16 * i + quad * 4 + r;
          int n = col0 + wc + 16 * j + l16;
          C[(size_t)m * EMBED + n] = __float2bfloat16(acc[i][j][r]);
        }
  } else {
#pragma unroll
    for (int i = 0; i < 2; ++i)
#pragma unroll
      for (int j = 0; j < 4; ++j)
#pragma unroll
        for (int r = 0; r < 4; ++r) {
          int m = row0 + wr + 16 * i + quad * 4 + r;
          int n = col0 + wc + 16 * j + l16;
          int b = m >> 11, s = m & (SEQ - 1);
          int h = n >> 6,  d = n & (HDIM - 1);
          Vto[(((size_t)(b * NHEAD + h)) * HDIM + d) * SEQ + s] =
              __float2bfloat16(acc[i][j][r]);
        }
  }
}

// Output projection, 64x64 tiles. Grid (64,16)=1024 blocks (4/CU).
__global__ __launch_bounds__(256, 4)
void out_proj_kernel(const bf16* __restrict__ X, const void* W,
                     const uint32_t* __restrict__ qref, void* C) {
  __shared__ __align__(16) bf16 sA[2 * 64 * 64];
  __shared__ __align__(16) bf16 sB[2 * 64 * 64];
  const int t    = threadIdx.x;
  const int wave = t >> 6, lane = t & 63;
  const int quad = lane >> 4, l16 = lane & 15;
  const int row0 = blockIdx.x * 64;
  const int col0 = blockIdx.y * 64;
  const int wr = (wave & 1) * 32;
  const int wc = (wave >> 1) * 32;
  const bool isbf = detect_bf16(qref, t);

  f32x4 acc[2][2] = {};
  if (isbf)
    gemm_nt_dbuf<64, 64>(X, (const bf16*)W, sA, sB, acc,
                         row0, col0, t, wr, wc, l16, quad);
  else
    gemm_nt_slow<64, 64, true, false>(X, W, sA, sB, acc,
                                      row0, col0, t, wr, wc, l16, quad);

#pragma unroll
  for (int i = 0; i < 2; ++i)
#pragma unroll
    for (int j = 0; j < 2; ++j)
#pragma unroll
      for (int r = 0; r < 4; ++r) {
        int m = row0 + wr + 16 * i + quad * 4 + r;
        int n = col0 + wc + 16 * j + l16;
        if (isbf)
          ((bf16*)C)[(size_t)m * EMBED + n] = __float2bfloat16(acc[i][j][r]);
        else
          ((float*)C)[(size_t)m * EMBED + n] = acc[i][j][r];
      }
}

// ---------------------------------------------------------------------------
// Flash attention v4: fixed-shift softmax + dbuf K/V. Block = 64 q-rows
// (4 waves x 16 rows), grid (32,16,2)=1024 (4/CU), LDS 49 KB (3 resident).
// ---------------------------------------------------------------------------
#define SM_C1 0.18033688011112042f    // 0.125 * log2(e)
#define SM_C0 -14.426950408889634f    // -10 * log2(e)

__global__ __launch_bounds__(256, 3)
void flash_kernel(const bf16* __restrict__ Q, const bf16* __restrict__ K,
                  const bf16* __restrict__ Vt, bf16* __restrict__ O) {
  __shared__ __align__(16) bf16 sQ[64 * 64];
  __shared__ __align__(16) bf16 sK[2][64 * 64];
  __shared__ __align__(16) bf16 sV[2][64 * 64];   // [dim][key]
  __shared__ __align__(16) bf16 sP[4][16 * 72];   // per-wave P, padded stride

  const int t    = threadIdx.x;
  const int wave = t >> 6, lane = t & 63;
  const int quad = lane >> 4, l16 = lane & 15;
  const int b  = blockIdx.z;
  const int h  = blockIdx.y;
  const int q0 = blockIdx.x * 64;

  const bf16* Qg = Q + ((size_t)b * SEQ + q0) * EMBED + h * HDIM;
  const bf16* Kg = K + ((size_t)b * SEQ) * EMBED + h * HDIM;
  const bf16* Vg = Vt + (((size_t)(b * NHEAD + h)) * HDIM) * SEQ;  // [64][2048]

  // stage Q once (64x64) — oldest vm ops, retired by the first vmcnt wait
#pragma unroll
  for (int c = 0; c < 2; ++c) {
    int id = c * 256 + t;
    int r = id >> 3, cc = (id & 7) * 8;
    GLD16(Qg + (size_t)r * EMBED + cc, sQ + id * 8);
  }

  auto issueKV = [&](int kt, int buf) {
#pragma unroll
    for (int c = 0; c < 2; ++c) {
      int id = c * 256 + t;
      int r = id >> 3, cc = (id & 7) * 8;
      GLD16(Kg + (size_t)(kt + r) * EMBED + cc, &sK[buf][id * 8]);
      GLD16(Vg + (size_t)r * SEQ + kt + cc,     &sV[buf][id * 8]);
    }
  };

  f32x4 o_acc[4] = {};          // [d-tile tt], C-layout
  float lsum[4] = {};           // per-lane partial row sums

  auto tile_compute = [&](int buf) {
    f32x4 s_acc[4] = {};
#pragma unroll
    for (int kk = 0; kk < 64; kk += 32) {
      bf16x8 aq = *(const bf16x8*)(sQ + (16 * wave + l16) * 64 + kk + quad * 8);
#pragma unroll
      for (int tt = 0; tt < 4; ++tt) {
        bf16x8 bk = *(const bf16x8*)(&sK[buf][(16 * tt + l16) * 64 + kk + quad * 8]);
        s_acc[tt] = __builtin_amdgcn_mfma_f32_16x16x32_bf16(aq, bk, s_acc[tt], 0, 0, 0);
      }
    }

    // fixed-shift softmax: exp, per-lane sum, bf16 -> sP (A-layout rows)
#pragma unroll
    for (int tt = 0; tt < 4; ++tt)
#pragma unroll
      for (int r = 0; r < 4; ++r) {
        float p = __builtin_amdgcn_exp2f(fmaf(s_acc[tt][r], SM_C1, SM_C0));
        lsum[r] += p;
        sP[wave][(quad * 4 + r) * 72 + 16 * tt + l16] = __float2bfloat16(p);
      }
    asm volatile("s_waitcnt lgkmcnt(0)" ::: "memory");

    // O += P V : A-frag from sP (m=l16), B-frag from sV[dim][key]
#pragma unroll
    for (int kk = 0; kk < 64; kk += 32) {
      bf16x8 ap = *(const bf16x8*)(sP[wave] + l16 * 72 + kk + quad * 8);
#pragma unroll
      for (int tt = 0; tt < 4; ++tt) {
        bf16x8 bv = *(const bf16x8*)(&sV[buf][(16 * tt + l16) * 64 + kk + quad * 8]);
        o_acc[tt] = __builtin_amdgcn_mfma_f32_16x16x32_bf16(ap, bv, o_acc[tt], 0, 0, 0);
      }
    }
  };

  issueKV(0, 0);
  int p = 0;
  for (int it = 0; it < SEQ / 64 - 1; ++it) {
    issueKV((it + 1) * 64, p ^ 1);
    asm volatile("s_waitcnt vmcnt(4)\ns_barrier" ::: "memory");
    tile_compute(p);
    asm volatile("s_barrier" ::: "memory");
    p ^= 1;
  }
  asm volatile("s_waitcnt vmcnt(0)\ns_barrier" ::: "memory");
  tile_compute(p);

  // one-time row-sum reduction across the 16 lanes sharing each row
#pragma unroll
  for (int off = 1; off < 16; off <<= 1)
#pragma unroll
    for (int r = 0; r < 4; ++r)
      lsum[r] += __shfl_xor(lsum[r], off, 64);

  float inv[4];
#pragma unroll
  for (int r = 0; r < 4; ++r) inv[r] = 1.0f / lsum[r];

  bf16* Og = O + ((size_t)b * SEQ + q0 + 16 * wave) * EMBED + h * HDIM;
#pragma unroll
  for (int tt = 0; tt < 4; ++tt)
#pragma unroll
    for (int r = 0; r < 4; ++r)
      Og[(size_t)(quad * 4 + r) * EMBED + 16 * tt + l16] =
          __float2bfloat16(o_acc[tt][r] * inv[r]);
}

extern "C" void kernel_launch(void* const* d_in, const int* in_sizes, int n_in,
                              void* d_out, int out_size, void* d_ws, size_t ws_size,
                              hipStream_t stream) {
  (void)in_sizes; (void)n_in; (void)out_size; (void)ws_size;
  bf16* Qp  = (bf16*)((char*)d_ws + 256);         // [4096][1024] bf16
  bf16* Kp  = Qp  + (size_t)MTOT * EMBED;         // [4096][1024] bf16
  bf16* Vtp = Kp  + (size_t)MTOT * EMBED;         // [B][H][D][S] bf16
  bf16* Op  = Vtp + (size_t)MTOT * EMBED;         // [4096][1024] bf16

  qkv_proj_kernel<<<dim3(64, 24), 256, 0, stream>>>(
      d_in[0], d_in[1], d_in[2], d_in[3], d_in[4], d_in[5], Qp, Kp, Vtp);
  flash_kernel<<<dim3(SEQ / 64, NHEAD, BATCH), 256, 0, stream>>>(Qp, Kp, Vtp, Op);
  out_proj_kernel<<<dim3(64, 16), 256, 0, stream>>>(Op, d_in[6],
                                                    (const uint32_t*)d_in[0], d_out);
}